// Round 8
// baseline (1822.862 us; speedup 1.0000x reference)
//
#include <hip/hip_runtime.h>
#include <math.h>

#define BB 512
#define SS 2048
#define DD 19
#define HH 40
#define CH 32
#define NCH (SS / CH)   // 64 chunks
#define RS 41           // ring stride: flat [64][41] -> 2-way max both access patterns
#define HS 48           // h buffer stride (16B aligned)

// quad_perm DPP: lane reads within its quad. xor1=[1,0,3,2]=0xB1, xor2=[2,3,0,1]=0x4E, xor3=[3,2,1,0]=0x1B
#define QPERM(v, ctrl) __int_as_float(__builtin_amdgcn_mov_dpp(__float_as_int(v), (ctrl), 0xf, 0xf, true))

__device__ __forceinline__ float gate_act(float a, float mulk) {
    // mulk=1: sigmoid(a); mulk=2: tanh(a). 1 - mulk/(exp(mulk*a)+1), NaN-free.
    float e = __expf(a * mulk);
    float r = __builtin_amdgcn_rcpf(e + 1.0f);
    return fmaf(-mulk, r, 1.0f);
}
__device__ __forceinline__ float tanh_fast(float x) {
    float e = __expf(2.0f * x);
    float r = __builtin_amdgcn_rcpf(e + 1.0f);
    return fmaf(-2.0f, r, 1.0f);
}
__device__ __forceinline__ float sigm_fast(float x) {
    float e = __expf(x);
    float r = __builtin_amdgcn_rcpf(e + 1.0f);
    return fmaf(-1.0f, r, 1.0f);
}

__global__ __launch_bounds__(256, 1)  // 1 wave/EU min -> VGPR cap 512 (paired state + weights, no spill)
void lstm_fused(const float* __restrict__ x,
                const float* __restrict__ W_ih,
                const float* __restrict__ W_hh,
                const float* __restrict__ b_ih,
                const float* __restrict__ b_hh,
                const float* __restrict__ ln_g,
                const float* __restrict__ ln_b,
                const float* __restrict__ W1,
                const float* __restrict__ b1,
                const float* __restrict__ W2,
                const float* __restrict__ b2,
                const float* __restrict__ Wo,
                const float* __restrict__ bo,
                const float* __restrict__ log_thr,
                float* __restrict__ out) {
    __shared__ float s_ring[2][CH][RS];            // [elem][t][unit], flat [64][41]
    __shared__ __align__(16) float s_h[2][2][HS];  // [elem][buf][unit]
    __shared__ __align__(16) float s_x[2][CH][20]; // [elem][t][d], [19]=pad
    __shared__ __align__(16) float s_W1[HH * HH];
    __shared__ __align__(16) float s_W2[HH * HH];
    __shared__ float s_lng[HH], s_lnb[HH], s_Wo[HH], s_b1[HH], s_b2[HH];
    __shared__ float s_part[256];

    const int tid = threadIdx.x;
    const int blk = blockIdx.x;
    const int b0 = 2 * blk;               // this block owns batch elements b0, b0+1

    // ---- cooperative staging of post-LSTM weights ----
    for (int i = tid; i < HH * HH; i += 256) { s_W1[i] = W1[i]; s_W2[i] = W2[i]; }
    if (tid < HH) {
        s_lng[tid] = ln_g[tid]; s_lnb[tid] = ln_b[tid]; s_Wo[tid] = Wo[tid];
        s_b1[tid] = b1[tid]; s_b2[tid] = b2[tid];
    }
    if (tid < HS) {
        s_h[0][0][tid] = 0.0f; s_h[0][1][tid] = 0.0f;
        s_h[1][0][tid] = 0.0f; s_h[1][1][tid] = 0.0f;
    }

    const float bo0 = bo[0];
    const float thrv = expf(log_thr[0]);

    // ---- gate thread setup: thread 4u+g owns gate row g*40+u (both elements) ----
    const bool isGate = tid < 4 * HH;     // 160 gate threads
    const int g = tid & 3;
    const int u = tid >> 2;
    const int grow = g * HH + u;
    const float mulk = (g == 2) ? 2.0f : 1.0f;

    float wih[DD];
    float whh[HH];
    float bsum = 0.0f;
    if (isGate) {
#pragma unroll
        for (int d = 0; d < DD; ++d) wih[d] = W_ih[grow * DD + d];
        const float4* wr = (const float4*)&W_hh[grow * HH];
#pragma unroll
        for (int q = 0; q < 10; ++q) {
            float4 f = wr[q];
            whh[4*q] = f.x; whh[4*q+1] = f.y; whh[4*q+2] = f.z; whh[4*q+3] = f.w;
        }
        bsum = b_ih[grow] + b_hh[grow];
    }
    float cc0 = 0.f, hh0 = 0.f, cc1 = 0.f, hh1 = 0.f;   // live in g==0 lanes

    // ---- x prefetch: 2 elems * 608 = 1216 floats, 5 regs/thread ----
    float* sxf = &s_x[0][0][0];           // flat [2*CH*20]
    const int i0 = tid, i1 = tid + 256, i2 = tid + 512, i3 = tid + 768, i4 = tid + 1024;
    const int e0_ = i0 / 608, r0_ = i0 % 608;
    const int e1_ = i1 / 608, r1_ = i1 % 608;
    const int e2_ = i2 / 608, r2_ = i2 % 608;
    const int e3_ = i3 / 608, r3_ = i3 % 608;
    const int e4_ = i4 / 608, r4_ = i4 % 608;
    const int l0_ = e0_ * (CH*20) + (r0_/DD)*20 + (r0_%DD);
    const int l1_ = e1_ * (CH*20) + (r1_/DD)*20 + (r1_%DD);
    const int l2_ = e2_ * (CH*20) + (r2_/DD)*20 + (r2_%DD);
    const int l3_ = e3_ * (CH*20) + (r3_/DD)*20 + (r3_%DD);
    const int l4_ = e4_ * (CH*20) + (r4_/DD)*20 + (r4_%DD);
    const size_t go0 = (size_t)e0_ * SS * DD + r0_;
    const size_t go1 = (size_t)e1_ * SS * DD + r1_;
    const size_t go2 = (size_t)e2_ * SS * DD + r2_;
    const size_t go3 = (size_t)e3_ * SS * DD + r3_;
    const size_t go4 = (size_t)e4_ * SS * DD + r4_;
    const bool has4 = (i4 < 2 * CH * DD);

    float xr0, xr1, xr2, xr3, xr4 = 0.f;
    {
        const float* xp = x + (size_t)b0 * SS * DD;   // chunk 0
        xr0 = xp[go0]; xr1 = xp[go1]; xr2 = xp[go2]; xr3 = xp[go3];
        if (has4) xr4 = xp[go4];
    }

    __syncthreads();   // weights + h init visible

    for (int ch = 0; ch < NCH; ++ch) {
        // ---- stage x chunk (both elems) from prefetch regs; issue next chunk ----
        sxf[l0_] = xr0; sxf[l1_] = xr1; sxf[l2_] = xr2; sxf[l3_] = xr3;
        if (has4) sxf[l4_] = xr4;
        if (ch + 1 < NCH) {
            const float* xp = x + (size_t)b0 * SS * DD + (size_t)(ch + 1) * CH * DD;
            xr0 = xp[go0]; xr1 = xp[go1]; xr2 = xp[go2]; xr3 = xp[go3];
            if (has4) xr4 = xp[go4];
        }
        __syncthreads();

        // ---- 32 recurrent steps x 2 elements, ONE barrier each ----
        for (int t = 0; t < CH; ++t) {
            if (isGate) {
                const float4* h40 = (const float4*)s_h[0][t & 1];
                const float4* h41 = (const float4*)s_h[1][t & 1];
                const float4* x40 = (const float4*)&s_x[0][t][0];
                const float4* x41 = (const float4*)&s_x[1][t][0];
                float a00 = bsum, a01 = 0.f, a02 = 0.f, a03 = 0.f;
                float a10 = bsum, a11 = 0.f, a12 = 0.f, a13 = 0.f;
                float4 f0, f1;
                f0 = x40[0]; f1 = x41[0];
                a00 = fmaf(f0.x, wih[0], a00); a01 = fmaf(f0.y, wih[1], a01);
                a02 = fmaf(f0.z, wih[2], a02); a03 = fmaf(f0.w, wih[3], a03);
                a10 = fmaf(f1.x, wih[0], a10); a11 = fmaf(f1.y, wih[1], a11);
                a12 = fmaf(f1.z, wih[2], a12); a13 = fmaf(f1.w, wih[3], a13);
                f0 = x40[1]; f1 = x41[1];
                a00 = fmaf(f0.x, wih[4], a00); a01 = fmaf(f0.y, wih[5], a01);
                a02 = fmaf(f0.z, wih[6], a02); a03 = fmaf(f0.w, wih[7], a03);
                a10 = fmaf(f1.x, wih[4], a10); a11 = fmaf(f1.y, wih[5], a11);
                a12 = fmaf(f1.z, wih[6], a12); a13 = fmaf(f1.w, wih[7], a13);
                f0 = x40[2]; f1 = x41[2];
                a00 = fmaf(f0.x, wih[8], a00); a01 = fmaf(f0.y, wih[9], a01);
                a02 = fmaf(f0.z, wih[10], a02); a03 = fmaf(f0.w, wih[11], a03);
                a10 = fmaf(f1.x, wih[8], a10); a11 = fmaf(f1.y, wih[9], a11);
                a12 = fmaf(f1.z, wih[10], a12); a13 = fmaf(f1.w, wih[11], a13);
                f0 = x40[3]; f1 = x41[3];
                a00 = fmaf(f0.x, wih[12], a00); a01 = fmaf(f0.y, wih[13], a01);
                a02 = fmaf(f0.z, wih[14], a02); a03 = fmaf(f0.w, wih[15], a03);
                a10 = fmaf(f1.x, wih[12], a10); a11 = fmaf(f1.y, wih[13], a11);
                a12 = fmaf(f1.z, wih[14], a12); a13 = fmaf(f1.w, wih[15], a13);
                f0 = x40[4]; f1 = x41[4];
                a00 = fmaf(f0.x, wih[16], a00); a01 = fmaf(f0.y, wih[17], a01);
                a02 = fmaf(f0.z, wih[18], a02);
                a10 = fmaf(f1.x, wih[16], a10); a11 = fmaf(f1.y, wih[17], a11);
                a12 = fmaf(f1.z, wih[18], a12);
                // h part: 40 FMAs per element
#pragma unroll
                for (int q = 0; q < 10; ++q) {
                    float4 h0 = h40[q], h1 = h41[q];
                    a00 = fmaf(h0.x, whh[4*q+0], a00);
                    a01 = fmaf(h0.y, whh[4*q+1], a01);
                    a02 = fmaf(h0.z, whh[4*q+2], a02);
                    a03 = fmaf(h0.w, whh[4*q+3], a03);
                    a10 = fmaf(h1.x, whh[4*q+0], a10);
                    a11 = fmaf(h1.y, whh[4*q+1], a11);
                    a12 = fmaf(h1.z, whh[4*q+2], a12);
                    a13 = fmaf(h1.w, whh[4*q+3], a13);
                }
                float acc0 = (a00 + a01) + (a02 + a03);
                float acc1 = (a10 + a11) + (a12 + a13);
                float av0 = gate_act(acc0, mulk);
                float av1 = gate_act(acc1, mulk);
                // quad_perm DPP: depth-1, VALU-only (no LDS pipe)
                float bv0 = QPERM(av0, 0xB1), cv0 = QPERM(av0, 0x4E), dv0 = QPERM(av0, 0x1B);
                float bv1 = QPERM(av1, 0xB1), cv1 = QPERM(av1, 0x4E), dv1 = QPERM(av1, 0x1B);
                // lane 4u+0: av=i, bv=f, cv=g~, dv=o
                if (g == 0) {
                    cc0 = fmaf(bv0, cc0, av0 * cv0);
                    cc1 = fmaf(bv1, cc1, av1 * cv1);
                    hh0 = dv0 * tanh_fast(cc0);
                    hh1 = dv1 * tanh_fast(cc1);
                    s_h[0][(t + 1) & 1][u] = hh0;
                    s_h[1][(t + 1) & 1][u] = hh1;
                    s_ring[0][t][u] = hh0;
                    s_ring[1][t][u] = hh1;
                }
            }
            __syncthreads();
        }

        // ---- consume: 64 rows (2 elems x 32 steps), 4 threads/row x 10 rows ----
        {
            const int row = tid & 63;          // flat row in [64][41] ring
            const int e = row >> 5, s = row & 31;
            const int q4 = tid >> 6;           // 0..3 (wave index)
            const float* rrow = &s_ring[e][s][0];
            float hv[HH];
#pragma unroll
            for (int k = 0; k < HH; ++k) hv[k] = rrow[k];
            float m0 = 0.f, m1 = 0.f, q0 = 0.f, q1 = 0.f;
#pragma unroll
            for (int k = 0; k < HH; k += 2) {
                m0 += hv[k]; m1 += hv[k + 1];
                q0 = fmaf(hv[k], hv[k], q0); q1 = fmaf(hv[k + 1], hv[k + 1], q1);
            }
            float mu = (m0 + m1) * (1.0f / HH);
            float var = (q0 + q1) * (1.0f / HH) - mu * mu;
            float inv = 1.0f / sqrtf(var + 1e-5f);
#pragma unroll
            for (int k = 0; k < HH; ++k)
                hv[k] = fmaf((hv[k] - mu) * inv, s_lng[k], s_lnb[k]);  // hv := ln
            // sigWo: STATIC full loop (rule #20), kept only by q4==0
            float part = 0.f;
#pragma unroll
            for (int k = 0; k < HH; ++k)
                part = fmaf(sigm_fast(hv[k]), s_Wo[k], part);
            if (q4 != 0) part = 0.f;
            __syncthreads();   // all ring reads done -> reuse ring for r1
            float r1v[10];
#pragma unroll
            for (int jj = 0; jj < 10; ++jj) {
                int j = q4 * 10 + jj;
                const float4* wr = (const float4*)&s_W1[j * HH];
                float a0 = s_b1[j], a1 = 0.f;
#pragma unroll
                for (int q = 0; q < 10; ++q) {
                    float4 w4 = wr[q];
                    a0 = fmaf(w4.x, hv[4*q+0], a0); a1 = fmaf(w4.y, hv[4*q+1], a1);
                    a0 = fmaf(w4.z, hv[4*q+2], a0); a1 = fmaf(w4.w, hv[4*q+3], a1);
                }
                r1v[jj] = tanh_fast(a0 + a1);
                s_ring[e][s][j] = r1v[jj];
            }
            __syncthreads();
            float rr[HH];
#pragma unroll
            for (int k = 0; k < HH; ++k) rr[k] = rrow[k];
#pragma unroll
            for (int jj = 0; jj < 10; ++jj) {
                int j = q4 * 10 + jj;
                const float4* wr = (const float4*)&s_W2[j * HH];
                float a0 = s_b2[j], a1 = 0.f;
#pragma unroll
                for (int q = 0; q < 10; ++q) {
                    float4 w4 = wr[q];
                    a0 = fmaf(w4.x, rr[4*q+0], a0); a1 = fmaf(w4.y, rr[4*q+1], a1);
                    a0 = fmaf(w4.z, rr[4*q+2], a0); a1 = fmaf(w4.w, rr[4*q+3], a1);
                }
                float r2 = tanh_fast(a0 + a1);
                part = fmaf(r2, s_Wo[j], part);
            }
            s_part[tid] = part;
            __syncthreads();
            if (tid < 64) {
                const int ee = tid >> 5, ss2 = tid & 31;
                float tot = bo0;
#pragma unroll
                for (int qq = 0; qq < 4; ++qq) tot += s_part[qq * 64 + tid];
                float raw = tanh_fast(tot);
                float sg = (fabsf(raw) >= thrv) ? raw : 0.0f;
                out[(size_t)(b0 + ee) * SS + (size_t)ch * CH + ss2] = sg;
            }
        }
    }

    // ---- final states + threshold scalar ----
    if (isGate && g == 0) {
        out[(size_t)BB * SS + (size_t)b0 * HH + u] = hh0;
        out[(size_t)BB * SS + (size_t)(b0 + 1) * HH + u] = hh1;
        out[(size_t)BB * SS + (size_t)BB * HH + (size_t)b0 * HH + u] = cc0;
        out[(size_t)BB * SS + (size_t)BB * HH + (size_t)(b0 + 1) * HH + u] = cc1;
    }
    if (blk == 0 && tid == 0) {
        out[(size_t)BB * SS + 2 * (size_t)BB * HH] = thrv;
    }
}

extern "C" void kernel_launch(void* const* d_in, const int* in_sizes, int n_in,
                              void* d_out, int out_size, void* d_ws, size_t ws_size,
                              hipStream_t stream) {
    const float* x    = (const float*)d_in[0];
    const float* W_ih = (const float*)d_in[1];
    const float* W_hh = (const float*)d_in[2];
    const float* b_ih = (const float*)d_in[3];
    const float* b_hh = (const float*)d_in[4];
    const float* ln_g = (const float*)d_in[5];
    const float* ln_b = (const float*)d_in[6];
    const float* W1   = (const float*)d_in[7];
    const float* b1   = (const float*)d_in[8];
    const float* W2   = (const float*)d_in[9];
    const float* b2   = (const float*)d_in[10];
    const float* Wo   = (const float*)d_in[11];
    const float* bo   = (const float*)d_in[12];
    const float* lt   = (const float*)d_in[13];
    float* out = (float*)d_out;

    lstm_fused<<<dim3(BB / 2), dim3(256), 0, stream>>>(
        x, W_ih, W_hh, b_ih, b_hh, ln_g, ln_b, W1, b1, W2, b2, Wo, bo, lt, out);
}